// Round 1
// baseline (978.232 us; speedup 1.0000x reference)
//
#include <hip/hip_runtime.h>

#define B_   16
#define C_   512
#define HW_  1024
#define G_   32
#define CPG  16            // C_/G_
#define EPS  1e-5f
#define CHW  ((size_t)C_ * HW_)        // 524288 per-batch stride
#define HW2  ((size_t)HW_ * HW_)       // 1048576 attn per-batch stride

// ---------------- GroupNorm ----------------
// one block per (batch, group): 16 channels x 1024 spatial = 16384 floats
__global__ __launch_bounds__(256) void gn_kernel(
    const float* __restrict__ x, const float* __restrict__ scale,
    const float* __restrict__ bias, float* __restrict__ hn)
{
    int bg = blockIdx.x;               // 0..511
    int b = bg / G_, g = bg % G_;
    const float* xp = x + ((size_t)b * C_ + (size_t)g * CPG) * HW_;
    float* hp = hn + ((size_t)b * C_ + (size_t)g * CPG) * HW_;
    const int N = CPG * HW_;           // 16384

    float s = 0.f, ss = 0.f;
    for (int i = threadIdx.x; i < N; i += 256) {
        float v = xp[i];
        s += v; ss += v * v;
    }
    // wave reduce (wave = 64)
    for (int off = 32; off; off >>= 1) {
        s  += __shfl_down(s,  off, 64);
        ss += __shfl_down(ss, off, 64);
    }
    __shared__ float red0[4], red1[4];
    int lane = threadIdx.x & 63, wid = threadIdx.x >> 6;
    if (lane == 0) { red0[wid] = s; red1[wid] = ss; }
    __syncthreads();
    __shared__ float smu, sinv;
    if (threadIdx.x == 0) {
        float S  = red0[0] + red0[1] + red0[2] + red0[3];
        float SS = red1[0] + red1[1] + red1[2] + red1[3];
        float mu = S / (float)N;
        float var = SS / (float)N - mu * mu;
        smu = mu; sinv = rsqrtf(var + EPS);
    }
    __syncthreads();
    float mu = smu, inv = sinv;
    for (int i = threadIdx.x; i < N; i += 256) {
        int c = g * CPG + (i >> 10);   // i / HW_
        hp[i] = (xp[i] - mu) * inv * scale[c] + bias[c];
    }
}

// ---------------- Tiled fp32 GEMM ----------------
// C[m,n] = alpha * sum_k A[m,k]*B[k,n] (+ bias[m]) (+ res[m,n])
// TA: A stored as A[k*lda + m]  (transposed);  else A[m*lda + k]
// TB: B stored as B[n*ldb + k]  (transposed);  else B[k*ldb + n]
// BM=BN=64, BK=16, 256 threads, 4x4 acc per thread.
template<bool TA, bool TB, bool HAS_BIAS, bool HAS_RES>
__global__ __launch_bounds__(256) void gemm_kernel(
    const float* __restrict__ A, size_t strideA, int lda,
    const float* __restrict__ Bm, size_t strideB, int ldb,
    float* __restrict__ Cm, size_t strideC,
    const float* __restrict__ bias,
    const float* __restrict__ res, size_t strideR,
    int N, int K, float alpha)
{
    const int bz = blockIdx.z;
    const float* Ab = A  + (size_t)bz * strideA;
    const float* Bb = Bm + (size_t)bz * strideB;
    float*       Cb = Cm + (size_t)bz * strideC;

    const int m0 = blockIdx.y * 64;
    const int n0 = blockIdx.x * 64;

    __shared__ float As[16][68];       // row stride 68 floats: 16B-aligned rows
    __shared__ float Bs[16][68];

    const int t  = threadIdx.x;
    const int tm = (t & 15) * 4;
    const int tn = (t >> 4) * 4;

    float acc[4][4] = {};

    for (int k0 = 0; k0 < K; k0 += 16) {
#pragma unroll
        for (int i = 0; i < 4; ++i) {
            int idx = i * 256 + t;
            if (TA) {
                int m = idx & 63, kk = idx >> 6;
                As[kk][m] = Ab[(size_t)(k0 + kk) * lda + (m0 + m)];
            } else {
                int kk = idx & 15, m = idx >> 4;
                As[kk][m] = Ab[(size_t)(m0 + m) * lda + (k0 + kk)];
            }
            if (TB) {
                int kk = idx & 15, n = idx >> 4;
                Bs[kk][n] = Bb[(size_t)(n0 + n) * ldb + (k0 + kk)];
            } else {
                int n = idx & 63, kk = idx >> 6;
                Bs[kk][n] = Bb[(size_t)(k0 + kk) * ldb + (n0 + n)];
            }
        }
        __syncthreads();
#pragma unroll
        for (int kk = 0; kk < 16; ++kk) {
            float4 av = *reinterpret_cast<const float4*>(&As[kk][tm]);
            float4 bv = *reinterpret_cast<const float4*>(&Bs[kk][tn]);
            float a[4] = {av.x, av.y, av.z, av.w};
            float b[4] = {bv.x, bv.y, bv.z, bv.w};
#pragma unroll
            for (int i = 0; i < 4; ++i)
#pragma unroll
                for (int j = 0; j < 4; ++j)
                    acc[i][j] = fmaf(a[i], b[j], acc[i][j]);
        }
        __syncthreads();
    }

#pragma unroll
    for (int i = 0; i < 4; ++i) {
        int m = m0 + tm + i;
        float bi = HAS_BIAS ? bias[m] : 0.f;
        size_t off = (size_t)m * N + (n0 + tn);
        float4 o;
        o.x = acc[i][0] * alpha + bi;
        o.y = acc[i][1] * alpha + bi;
        o.z = acc[i][2] * alpha + bi;
        o.w = acc[i][3] * alpha + bi;
        if (HAS_RES) {
            const float* rp = res + (size_t)bz * strideR + off;
            float4 r = *reinterpret_cast<const float4*>(rp);
            o.x += r.x; o.y += r.y; o.z += r.z; o.w += r.w;
        }
        *reinterpret_cast<float4*>(&Cb[off]) = o;
    }
}

// ---------------- row softmax over 1024 ----------------
__global__ __launch_bounds__(256) void softmax_kernel(float* __restrict__ attn)
{
    size_t row = blockIdx.x;
    float* p = attn + row * (size_t)HW_;
    float4 v = reinterpret_cast<float4*>(p)[threadIdx.x];

    float mx = fmaxf(fmaxf(v.x, v.y), fmaxf(v.z, v.w));
    for (int off = 32; off; off >>= 1) mx = fmaxf(mx, __shfl_down(mx, off, 64));
    __shared__ float redm[4], reds[4];
    int lane = threadIdx.x & 63, wid = threadIdx.x >> 6;
    if (lane == 0) redm[wid] = mx;
    __syncthreads();
    mx = fmaxf(fmaxf(redm[0], redm[1]), fmaxf(redm[2], redm[3]));

    v.x = __expf(v.x - mx); v.y = __expf(v.y - mx);
    v.z = __expf(v.z - mx); v.w = __expf(v.w - mx);
    float s = v.x + v.y + v.z + v.w;
    for (int off = 32; off; off >>= 1) s += __shfl_down(s, off, 64);
    if (lane == 0) reds[wid] = s;
    __syncthreads();
    s = reds[0] + reds[1] + reds[2] + reds[3];

    float inv = 1.0f / s;
    v.x *= inv; v.y *= inv; v.z *= inv; v.w *= inv;
    reinterpret_cast<float4*>(p)[threadIdx.x] = v;
}

extern "C" void kernel_launch(void* const* d_in, const int* in_sizes, int n_in,
                              void* d_out, int out_size, void* d_ws, size_t ws_size,
                              hipStream_t stream)
{
    const float* x        = (const float*)d_in[0];
    // d_in[1] = temb : unused by the reference
    const float* gn_scale = (const float*)d_in[2];
    const float* gn_bias  = (const float*)d_in[3];
    const float* wq = (const float*)d_in[4];
    const float* bq = (const float*)d_in[5];
    const float* wk = (const float*)d_in[6];
    const float* bk = (const float*)d_in[7];
    const float* wv = (const float*)d_in[8];
    const float* bv = (const float*)d_in[9];
    const float* wo = (const float*)d_in[10];
    const float* bo = (const float*)d_in[11];
    float* out = (float*)d_out;

    float* ws = (float*)d_ws;
    const size_t E = (size_t)B_ * C_ * HW_;    // 8388608
    float* hn   = ws;                          // E floats
    float* q    = ws + E;
    float* km   = ws + 2 * E;
    float* v    = ws + 3 * E;
    float* attn = ws + 4 * E;                  // B*HW*HW = 16777216 floats
    float* ao   = hn;                          // hn dead after QKV -> reuse

    const float inv_sqrt_c = 0.044194173824159216f;   // 512^-0.5

    gn_kernel<<<dim3(B_ * G_), dim3(256), 0, stream>>>(x, gn_scale, gn_bias, hn);

    // QKV projections: (512x512)@(512x1024) per batch
    dim3 gqkv(HW_ / 64, C_ / 64, B_);
    gemm_kernel<false, false, true, false><<<gqkv, 256, 0, stream>>>(
        wq, 0, C_, hn, CHW, HW_, q,  CHW, bq, nullptr, 0, HW_, C_, 1.0f);
    gemm_kernel<false, false, true, false><<<gqkv, 256, 0, stream>>>(
        wk, 0, C_, hn, CHW, HW_, km, CHW, bk, nullptr, 0, HW_, C_, 1.0f);
    gemm_kernel<false, false, true, false><<<gqkv, 256, 0, stream>>>(
        wv, 0, C_, hn, CHW, HW_, v,  CHW, bv, nullptr, 0, HW_, C_, 1.0f);

    // scores = q^T k * C^-0.5 : (1024x512)^T-form @ (512x1024)
    dim3 gsc(HW_ / 64, HW_ / 64, B_);
    gemm_kernel<true, false, false, false><<<gsc, 256, 0, stream>>>(
        q, CHW, HW_, km, CHW, HW_, attn, HW2, nullptr, nullptr, 0, HW_, C_, inv_sqrt_c);

    softmax_kernel<<<dim3(B_ * HW_), dim3(256), 0, stream>>>(attn);

    // ao[c,i] = sum_j v[c,j] * attn[i,j]  -> A=v normal, B=attn transposed
    dim3 gpv(HW_ / 64, C_ / 64, B_);
    gemm_kernel<false, true, false, false><<<gpv, 256, 0, stream>>>(
        v, CHW, HW_, attn, HW2, HW_, ao, CHW, nullptr, nullptr, 0, HW_, HW_, 1.0f);

    // out = x + wo @ ao + bo
    gemm_kernel<false, false, true, true><<<gpv, 256, 0, stream>>>(
        wo, 0, C_, ao, CHW, HW_, out, CHW, bo, x, CHW, HW_, C_, 1.0f);
}

// Round 2
// 241.976 us; speedup vs baseline: 4.0427x; 4.0427x over previous
//
#include <hip/hip_runtime.h>

#define B_   16
#define C_   512
#define HW_  1024
#define G_   32
#define CPG  16
#define EPS  1e-5f
#define CHW  ((size_t)C_ * HW_)        // 524288 elements per batch (c,hw)
#define HW2  ((size_t)HW_ * HW_)       // 1048576 elements per batch (hw,hw)

typedef __attribute__((ext_vector_type(8))) short bf16x8;
typedef __attribute__((ext_vector_type(4))) float f32x4;

__device__ inline unsigned short f2bf(float f) {
    union { float f; unsigned u; } v; v.f = f;
    unsigned r = v.u + 0x7fffu + ((v.u >> 16) & 1u);   // RNE
    return (unsigned short)(r >> 16);
}
__device__ inline float bf2f(unsigned short h) {
    union { unsigned u; float f; } v; v.u = (unsigned)h << 16;
    return v.f;
}

__device__ inline void gload_lds16(const void* g, void* lds) {
    __builtin_amdgcn_global_load_lds(
        (const __attribute__((address_space(1))) void*)g,
        (__attribute__((address_space(3))) void*)lds,
        16, 0, 0);
}

// ---------------- fp32 -> bf16 weight convert ----------------
__global__ __launch_bounds__(256) void f2bf_kernel(const float* __restrict__ in,
                                                   unsigned short* __restrict__ out)
{
    int i = (blockIdx.x * 256 + threadIdx.x) * 4;
    float4 f = *reinterpret_cast<const float4*>(in + i);
    ushort4 o;
    o.x = f2bf(f.x); o.y = f2bf(f.y); o.z = f2bf(f.z); o.w = f2bf(f.w);
    *reinterpret_cast<ushort4*>(out + i) = o;
}

// ---------------- GroupNorm -> transposed bf16 hn_t[b][i][c] ----------------
__global__ __launch_bounds__(256) void gn_kernel(
    const float* __restrict__ x, const float* __restrict__ scale,
    const float* __restrict__ bias, unsigned short* __restrict__ hn_t)
{
    int bg = blockIdx.x;               // 0..511
    int b = bg / G_, g = bg % G_;
    const float* xp = x + ((size_t)b * C_ + (size_t)g * CPG) * HW_;
    const int N = CPG * HW_;           // 16384

    float s = 0.f, ss = 0.f;
    for (int i = threadIdx.x; i < N; i += 256) {
        float v = xp[i]; s += v; ss += v * v;
    }
    for (int off = 32; off; off >>= 1) {
        s  += __shfl_down(s,  off, 64);
        ss += __shfl_down(ss, off, 64);
    }
    __shared__ float red0[4], red1[4];
    int lane = threadIdx.x & 63, wid = threadIdx.x >> 6;
    if (lane == 0) { red0[wid] = s; red1[wid] = ss; }
    __syncthreads();
    __shared__ float smu, sinv;
    if (threadIdx.x == 0) {
        float S  = red0[0] + red0[1] + red0[2] + red0[3];
        float SS = red1[0] + red1[1] + red1[2] + red1[3];
        float mu = S / (float)N;
        float var = SS / (float)N - mu * mu;
        smu = mu; sinv = rsqrtf(var + EPS);
    }
    __syncthreads();
    float mu = smu, inv = sinv;

    float scl[CPG], bia[CPG];
#pragma unroll
    for (int cc = 0; cc < CPG; ++cc) {
        float sc = scale[g * CPG + cc];
        scl[cc] = sc * inv;
        bia[cc] = bias[g * CPG + cc] - mu * sc * inv;
    }
    for (int rep = 0; rep < 4; ++rep) {
        int i = rep * 256 + threadIdx.x;            // spatial index, coalesced reads
        __align__(16) unsigned short y[CPG];
#pragma unroll
        for (int cc = 0; cc < CPG; ++cc)
            y[cc] = f2bf(xp[cc * HW_ + i] * scl[cc] + bia[cc]);
        unsigned short* dst = hn_t + ((size_t)b * HW_ + i) * C_ + g * CPG;
        *reinterpret_cast<uint4*>(dst)     = *reinterpret_cast<uint4*>(&y[0]);
        *reinterpret_cast<uint4*>(dst + 8) = *reinterpret_cast<uint4*>(&y[8]);
    }
}

// ---------------- NT bf16 MFMA GEMM ----------------
// C[m][n] = alpha * sum_k A[m*K+k] * B[n*K+k]  (+bias)  (+res)
// A: [M][K] bf16, B: [N][K] bf16, both K-contiguous. 128x128 tile, BK=32,
// 256 threads = 4 waves, each wave 64x64 = 4x4 fragments of 16x16x32 MFMA.
// BIASMODE: 0 none, 1 per-row (bias[m]), 2 per-col (bias[n]).
template<int OUTF32, int BIASMODE, int HASRES>
__global__ __launch_bounds__(256) void gemm_nt(
    const short* __restrict__ A, size_t sA,
    const short* __restrict__ Bm, size_t sB,
    void* __restrict__ Cm, size_t sC, int ldC,
    const float* __restrict__ bias,
    const float* __restrict__ res, size_t sR,
    int K, float alpha)
{
    __shared__ __align__(16) short lA[128 * 32];   // 8 KB
    __shared__ __align__(16) short lB[128 * 32];   // 8 KB

    const int bz = blockIdx.z;
    const short* Ab = A  + (size_t)bz * sA;
    const short* Bb = Bm + (size_t)bz * sB;

    const int m0 = blockIdx.y * 128;
    const int n0 = blockIdx.x * 128;

    const int t = threadIdx.x;
    const int wv = t >> 6, lane = t & 63;
    const int wrow = (wv >> 1) * 64, wcol = (wv & 1) * 64;

    const int sm = lane >> 2;            // staging: row within 16-row chunk
    const int sk = (lane & 3) * 8;       // staging: k element offset
    const int fr = lane & 15;            // fragment row (A) / col (B)
    const int kb = (lane >> 4) * 8;      // fragment k element offset

    f32x4 zero = {0.f, 0.f, 0.f, 0.f};
    f32x4 acc[4][4];
#pragma unroll
    for (int i = 0; i < 4; ++i)
#pragma unroll
        for (int j = 0; j < 4; ++j) acc[i][j] = zero;

    const int i0 = 2 * wv, i1 = 2 * wv + 1;        // this wave's staging chunks

    for (int k0 = 0; k0 < K; k0 += 32) {
        // global -> LDS: linear [128][32] tiles; lane l deposits at base + l*16B
        gload_lds16(Ab + (size_t)(m0 + i0 * 16 + sm) * K + k0 + sk, &lA[i0 * 512]);
        gload_lds16(Ab + (size_t)(m0 + i1 * 16 + sm) * K + k0 + sk, &lA[i1 * 512]);
        gload_lds16(Bb + (size_t)(n0 + i0 * 16 + sm) * K + k0 + sk, &lB[i0 * 512]);
        gload_lds16(Bb + (size_t)(n0 + i1 * 16 + sm) * K + k0 + sk, &lB[i1 * 512]);
        __syncthreads();                            // drains vmcnt before barrier

        bf16x8 af[4], bfg[4];
#pragma unroll
        for (int f = 0; f < 4; ++f) {
            af[f]  = *reinterpret_cast<const bf16x8*>(&lA[(wrow + f * 16 + fr) * 32 + kb]);
            bfg[f] = *reinterpret_cast<const bf16x8*>(&lB[(wcol + f * 16 + fr) * 32 + kb]);
        }
#pragma unroll
        for (int i = 0; i < 4; ++i)
#pragma unroll
            for (int j = 0; j < 4; ++j)
                acc[i][j] = __builtin_amdgcn_mfma_f32_16x16x32_bf16(af[i], bfg[j], acc[i][j], 0, 0, 0);
        __syncthreads();
    }

    // C/D layout: col = lane&15, row = (lane>>4)*4 + reg  [m89-verified]
    const int rq = (lane >> 4) * 4;
#pragma unroll
    for (int i = 0; i < 4; ++i) {
#pragma unroll
        for (int rg = 0; rg < 4; ++rg) {
            int row = m0 + wrow + i * 16 + rq + rg;
            float bm = (BIASMODE == 1) ? bias[row] : 0.f;
#pragma unroll
            for (int j = 0; j < 4; ++j) {
                int col = n0 + wcol + j * 16 + fr;
                float vv = acc[i][j][rg] * alpha + bm;
                if (BIASMODE == 2) vv += bias[col];
                size_t off = (size_t)row * ldC + col;
                if (HASRES) vv += res[(size_t)bz * sR + off];
                if (OUTF32) ((float*)Cm)[(size_t)bz * sC + off] = vv;
                else ((unsigned short*)Cm)[(size_t)bz * sC + off] = f2bf(vv);
            }
        }
    }
}

// ---------------- in-place bf16 row softmax over 1024 ----------------
__global__ __launch_bounds__(256) void softmax_kernel(unsigned short* __restrict__ attn)
{
    size_t row = blockIdx.x;
    unsigned short* p = attn + row * HW_;
    ushort4 raw = reinterpret_cast<ushort4*>(p)[threadIdx.x];
    float v0 = bf2f(raw.x), v1 = bf2f(raw.y), v2 = bf2f(raw.z), v3 = bf2f(raw.w);

    float mx = fmaxf(fmaxf(v0, v1), fmaxf(v2, v3));
    for (int off = 32; off; off >>= 1) mx = fmaxf(mx, __shfl_down(mx, off, 64));
    __shared__ float redm[4], reds[4];
    int lane = threadIdx.x & 63, wid = threadIdx.x >> 6;
    if (lane == 0) redm[wid] = mx;
    __syncthreads();
    mx = fmaxf(fmaxf(redm[0], redm[1]), fmaxf(redm[2], redm[3]));

    v0 = __expf(v0 - mx); v1 = __expf(v1 - mx);
    v2 = __expf(v2 - mx); v3 = __expf(v3 - mx);
    float sum = v0 + v1 + v2 + v3;
    for (int off = 32; off; off >>= 1) sum += __shfl_down(sum, off, 64);
    if (lane == 0) reds[wid] = sum;
    __syncthreads();
    sum = reds[0] + reds[1] + reds[2] + reds[3];

    float inv = 1.f / sum;
    ushort4 o;
    o.x = f2bf(v0 * inv); o.y = f2bf(v1 * inv);
    o.z = f2bf(v2 * inv); o.w = f2bf(v3 * inv);
    reinterpret_cast<ushort4*>(p)[threadIdx.x] = o;
}

extern "C" void kernel_launch(void* const* d_in, const int* in_sizes, int n_in,
                              void* d_out, int out_size, void* d_ws, size_t ws_size,
                              hipStream_t stream)
{
    const float* x        = (const float*)d_in[0];
    // d_in[1] = temb : unused by the reference
    const float* gn_scale = (const float*)d_in[2];
    const float* gn_bias  = (const float*)d_in[3];
    const float* wq = (const float*)d_in[4];
    const float* bq = (const float*)d_in[5];
    const float* wk = (const float*)d_in[6];
    const float* bk = (const float*)d_in[7];
    const float* wv = (const float*)d_in[8];
    const float* bv = (const float*)d_in[9];
    const float* wo = (const float*)d_in[10];
    const float* bo = (const float*)d_in[11];
    float* out = (float*)d_out;

    // workspace layout (bf16 elements)
    short* ws = (short*)d_ws;
    const size_t E = (size_t)B_ * C_ * HW_;        // 8388608
    short* hn_t = ws;                              // [b][i][c]
    short* q_t  = hn_t + E;                        // [b][i][c]
    short* k_t  = q_t + E;                         // [b][i][c]
    short* v    = k_t + E;                         // [b][c][j]
    short* ao_t = v + E;                           // [b][i][c]
    short* attn = ao_t + E;                        // [b][i][j]  (B*HW*HW)
    short* wsq  = attn + (size_t)B_ * HW2;
    short* wsk  = wsq + (size_t)C_ * C_;
    short* wsv  = wsk + (size_t)C_ * C_;
    short* wso  = wsv + (size_t)C_ * C_;

    const float inv_sqrt_c = 0.044194173824159216f;   // 512^-0.5

    // weights -> bf16 (each 512x512 = 262144 elems, 4 elems/thread)
    f2bf_kernel<<<dim3(256), 256, 0, stream>>>(wq, (unsigned short*)wsq);
    f2bf_kernel<<<dim3(256), 256, 0, stream>>>(wk, (unsigned short*)wsk);
    f2bf_kernel<<<dim3(256), 256, 0, stream>>>(wv, (unsigned short*)wsv);
    f2bf_kernel<<<dim3(256), 256, 0, stream>>>(wo, (unsigned short*)wso);

    gn_kernel<<<dim3(B_ * G_), 256, 0, stream>>>(x, gn_scale, gn_bias, (unsigned short*)hn_t);

    // q_t[i][co] = sum_c hn_t[i][c] * wq[co][c] + bq[co]   (per-col bias)
    dim3 gq(C_ / 128, HW_ / 128, B_);              // (4, 8, 16)
    gemm_nt<0, 2, 0><<<gq, 256, 0, stream>>>(
        hn_t, CHW, wsq, 0, q_t, CHW, C_, bq, nullptr, 0, C_, 1.0f);
    gemm_nt<0, 2, 0><<<gq, 256, 0, stream>>>(
        hn_t, CHW, wsk, 0, k_t, CHW, C_, bk, nullptr, 0, C_, 1.0f);

    // v[co][j] = sum_c wv[co][c] * hn_t[j][c] + bv[co]     (per-row bias)
    dim3 gv(HW_ / 128, C_ / 128, B_);              // (8, 4, 16)
    gemm_nt<0, 1, 0><<<gv, 256, 0, stream>>>(
        wsv, 0, hn_t, CHW, v, CHW, HW_, bv, nullptr, 0, C_, 1.0f);

    // attn[i][j] = (sum_c q_t[i][c] * k_t[j][c]) * C^-0.5
    dim3 gs(HW_ / 128, HW_ / 128, B_);             // (8, 8, 16)
    gemm_nt<0, 0, 0><<<gs, 256, 0, stream>>>(
        q_t, CHW, k_t, CHW, attn, HW2, HW_, nullptr, nullptr, 0, C_, inv_sqrt_c);

    softmax_kernel<<<dim3(B_ * HW_), 256, 0, stream>>>((unsigned short*)attn);

    // ao_t[i][c] = sum_j attn[i][j] * v[c][j]
    dim3 gp(C_ / 128, HW_ / 128, B_);              // (4, 8, 16)
    gemm_nt<0, 0, 0><<<gp, 256, 0, stream>>>(
        attn, HW2, v, CHW, ao_t, CHW, C_, nullptr, nullptr, 0, HW_, 1.0f);

    // out[co][i] = x + sum_c wo[co][c] * ao_t[i][c] + bo[co]
    dim3 go(HW_ / 128, C_ / 128, B_);              // (8, 4, 16)
    gemm_nt<1, 1, 1><<<go, 256, 0, stream>>>(
        wso, 0, ao_t, CHW, out, CHW, HW_, bo, x, CHW, C_, 1.0f);
}

// Round 3
// 190.292 us; speedup vs baseline: 5.1407x; 1.2716x over previous
//
#include <hip/hip_runtime.h>

#define B_   16
#define C_   512
#define HW_  1024
#define G_   32
#define CPG  16
#define EPS  1e-5f
#define CHW  ((size_t)C_ * HW_)        // 524288 elements per batch (c,hw)
#define HW2  ((size_t)HW_ * HW_)       // 1048576 elements per batch (hw,hw)

typedef __attribute__((ext_vector_type(8))) short bf16x8;
typedef __attribute__((ext_vector_type(4))) float f32x4;

__device__ inline unsigned short f2bf(float f) {
    union { float f; unsigned u; } v; v.f = f;
    unsigned r = v.u + 0x7fffu + ((v.u >> 16) & 1u);   // RNE
    return (unsigned short)(r >> 16);
}
__device__ inline float bf2f(unsigned short h) {
    union { unsigned u; float f; } v; v.u = (unsigned)h << 16;
    return v.f;
}

__device__ inline void gload_lds16(const void* g, void* lds) {
    __builtin_amdgcn_global_load_lds(
        (const __attribute__((address_space(1))) void*)g,
        (__attribute__((address_space(3))) void*)lds,
        16, 0, 0);
}

// ---------------- fp32 -> bf16 weight convert (all 4 weights, one launch) ----
__global__ __launch_bounds__(256) void f2bf4_kernel(
    const float* __restrict__ w0, const float* __restrict__ w1,
    const float* __restrict__ w2, const float* __restrict__ w3,
    unsigned short* __restrict__ o0, unsigned short* __restrict__ o1,
    unsigned short* __restrict__ o2, unsigned short* __restrict__ o3)
{
    int wsel = blockIdx.x >> 8;
    int blk  = blockIdx.x & 255;
    const float* in = (wsel == 0) ? w0 : (wsel == 1) ? w1 : (wsel == 2) ? w2 : w3;
    unsigned short* out = (wsel == 0) ? o0 : (wsel == 1) ? o1 : (wsel == 2) ? o2 : o3;
    int i = (blk * 256 + threadIdx.x) * 4;
    float4 f = *reinterpret_cast<const float4*>(in + i);
    ushort4 o;
    o.x = f2bf(f.x); o.y = f2bf(f.y); o.z = f2bf(f.z); o.w = f2bf(f.w);
    *reinterpret_cast<ushort4*>(out + i) = o;
}

// ---------------- GN pass 1: per-(b,g) mean / rsqrt(var) ----------------
__global__ __launch_bounds__(256) void gn_stats(const float* __restrict__ x,
                                                float2* __restrict__ stats)
{
    int bg = blockIdx.x;                                  // 0..511
    const float4* xp = reinterpret_cast<const float4*>(x + (size_t)bg * CPG * HW_);
    const int N = CPG * HW_;                              // 16384

    float s = 0.f, ss = 0.f;
#pragma unroll
    for (int k = 0; k < 16; ++k) {
        float4 v = xp[threadIdx.x + k * 256];
        s  += v.x + v.y + v.z + v.w;
        ss += v.x * v.x + v.y * v.y + v.z * v.z + v.w * v.w;
    }
    for (int off = 32; off; off >>= 1) {
        s  += __shfl_down(s,  off, 64);
        ss += __shfl_down(ss, off, 64);
    }
    __shared__ float red0[4], red1[4];
    int lane = threadIdx.x & 63, wid = threadIdx.x >> 6;
    if (lane == 0) { red0[wid] = s; red1[wid] = ss; }
    __syncthreads();
    if (threadIdx.x == 0) {
        float S  = red0[0] + red0[1] + red0[2] + red0[3];
        float SS = red1[0] + red1[1] + red1[2] + red1[3];
        float mu = S / (float)N;
        float var = SS / (float)N - mu * mu;
        stats[bg] = make_float2(mu, rsqrtf(var + EPS));
    }
}

// ---------------- GN pass 2: normalize + transpose -> bf16 hn_t[b][i][c] ----
// block: 64c x 64i tile. Coalesced fp32 reads, LDS transpose, uint4 bf16 writes.
__global__ __launch_bounds__(256) void gn_apply(
    const float* __restrict__ x, const float2* __restrict__ stats,
    const float* __restrict__ scale, const float* __restrict__ bias,
    unsigned short* __restrict__ hn_t)
{
    __shared__ unsigned short tile[64][72];               // pad 72: conflict-light

    const int b  = blockIdx.z;
    const int c0 = blockIdx.y * 64;
    const int i0 = blockIdx.x * 64;
    const int t  = threadIdx.x;

    const int r = t >> 2;                                 // local c row 0..63
    const int q = t & 3;                                  // i quarter (16 each)
    const int c = c0 + r;

    float2 st = stats[b * G_ + (c >> 4)];
    float scl = scale[c] * st.y;
    float bia = bias[c] - st.x * scl;

    const float* xp = x + ((size_t)b * C_ + c) * HW_ + i0 + q * 16;
#pragma unroll
    for (int u = 0; u < 4; ++u) {
        float4 v = *reinterpret_cast<const float4*>(xp + u * 4);
        int il = q * 16 + u * 4;
        tile[il + 0][r] = f2bf(v.x * scl + bia);
        tile[il + 1][r] = f2bf(v.y * scl + bia);
        tile[il + 2][r] = f2bf(v.z * scl + bia);
        tile[il + 3][r] = f2bf(v.w * scl + bia);
    }
    __syncthreads();

    // write: row i gets 64 consecutive c = 8 uint4; thread does chunks q, q+4
    const int il = t >> 2;
    unsigned short* dst = hn_t + ((size_t)b * HW_ + i0 + il) * C_ + c0;
    *reinterpret_cast<uint4*>(dst + q * 8)        = *reinterpret_cast<uint4*>(&tile[il][q * 8]);
    *reinterpret_cast<uint4*>(dst + (q + 4) * 8)  = *reinterpret_cast<uint4*>(&tile[il][(q + 4) * 8]);
}

// ---------------- NT bf16 MFMA GEMM ----------------
// C[m][n] = alpha * sum_k A[m*K+k] * B[n*K+k]  (+bias)  (+res)
// A: [M][K] bf16, B: [N][K] bf16, both K-contiguous. 128x128 tile, BK=32,
// 256 threads = 4 waves, each wave 64x64 = 4x4 fragments of 16x16x32 MFMA.
// BIASMODE: 0 none, 1 per-row (bias[m]), 2 per-col (bias[n]).
template<int OUTF32, int BIASMODE, int HASRES>
__global__ __launch_bounds__(256) void gemm_nt(
    const short* __restrict__ A, size_t sA,
    const short* __restrict__ Bm, size_t sB,
    void* __restrict__ Cm, size_t sC, int ldC,
    const float* __restrict__ bias,
    const float* __restrict__ res, size_t sR,
    int K, float alpha)
{
    __shared__ __align__(16) short lA[128 * 32];   // 8 KB
    __shared__ __align__(16) short lB[128 * 32];   // 8 KB

    const int bz = blockIdx.z;
    const short* Ab = A  + (size_t)bz * sA;
    const short* Bb = Bm + (size_t)bz * sB;

    const int m0 = blockIdx.y * 128;
    const int n0 = blockIdx.x * 128;

    const int t = threadIdx.x;
    const int wv = t >> 6, lane = t & 63;
    const int wrow = (wv >> 1) * 64, wcol = (wv & 1) * 64;

    const int sm = lane >> 2;            // staging: row within 16-row chunk
    const int sk = (lane & 3) * 8;       // staging: k element offset
    const int fr = lane & 15;            // fragment row (A) / col (B)
    const int kb = (lane >> 4) * 8;      // fragment k element offset

    f32x4 zero = {0.f, 0.f, 0.f, 0.f};
    f32x4 acc[4][4];
#pragma unroll
    for (int i = 0; i < 4; ++i)
#pragma unroll
        for (int j = 0; j < 4; ++j) acc[i][j] = zero;

    const int i0 = 2 * wv, i1 = 2 * wv + 1;        // this wave's staging chunks

    for (int k0 = 0; k0 < K; k0 += 32) {
        gload_lds16(Ab + (size_t)(m0 + i0 * 16 + sm) * K + k0 + sk, &lA[i0 * 512]);
        gload_lds16(Ab + (size_t)(m0 + i1 * 16 + sm) * K + k0 + sk, &lA[i1 * 512]);
        gload_lds16(Bb + (size_t)(n0 + i0 * 16 + sm) * K + k0 + sk, &lB[i0 * 512]);
        gload_lds16(Bb + (size_t)(n0 + i1 * 16 + sm) * K + k0 + sk, &lB[i1 * 512]);
        __syncthreads();

        bf16x8 af[4], bfg[4];
#pragma unroll
        for (int f = 0; f < 4; ++f) {
            af[f]  = *reinterpret_cast<const bf16x8*>(&lA[(wrow + f * 16 + fr) * 32 + kb]);
            bfg[f] = *reinterpret_cast<const bf16x8*>(&lB[(wcol + f * 16 + fr) * 32 + kb]);
        }
#pragma unroll
        for (int i = 0; i < 4; ++i)
#pragma unroll
            for (int j = 0; j < 4; ++j)
                acc[i][j] = __builtin_amdgcn_mfma_f32_16x16x32_bf16(af[i], bfg[j], acc[i][j], 0, 0, 0);
        __syncthreads();
    }

    // C/D layout: col = lane&15, row = (lane>>4)*4 + reg  [m89-verified]
    const int rq = (lane >> 4) * 4;
#pragma unroll
    for (int i = 0; i < 4; ++i) {
#pragma unroll
        for (int rg = 0; rg < 4; ++rg) {
            int row = m0 + wrow + i * 16 + rq + rg;
            float bm = (BIASMODE == 1) ? bias[row] : 0.f;
#pragma unroll
            for (int j = 0; j < 4; ++j) {
                int col = n0 + wcol + j * 16 + fr;
                float vv = acc[i][j][rg] * alpha + bm;
                if (BIASMODE == 2) vv += bias[col];
                size_t off = (size_t)row * ldC + col;
                if (HASRES) vv += res[(size_t)bz * sR + off];
                if (OUTF32) ((float*)Cm)[(size_t)bz * sC + off] = vv;
                else ((unsigned short*)Cm)[(size_t)bz * sC + off] = f2bf(vv);
            }
        }
    }
}

// ---------------- in-place bf16 row softmax over 1024 ----------------
__global__ __launch_bounds__(256) void softmax_kernel(unsigned short* __restrict__ attn)
{
    size_t row = blockIdx.x;
    unsigned short* p = attn + row * HW_;
    ushort4 raw = reinterpret_cast<ushort4*>(p)[threadIdx.x];
    float v0 = bf2f(raw.x), v1 = bf2f(raw.y), v2 = bf2f(raw.z), v3 = bf2f(raw.w);

    float mx = fmaxf(fmaxf(v0, v1), fmaxf(v2, v3));
    for (int off = 32; off; off >>= 1) mx = fmaxf(mx, __shfl_down(mx, off, 64));
    __shared__ float redm[4], reds[4];
    int lane = threadIdx.x & 63, wid = threadIdx.x >> 6;
    if (lane == 0) redm[wid] = mx;
    __syncthreads();
    mx = fmaxf(fmaxf(redm[0], redm[1]), fmaxf(redm[2], redm[3]));

    v0 = __expf(v0 - mx); v1 = __expf(v1 - mx);
    v2 = __expf(v2 - mx); v3 = __expf(v3 - mx);
    float sum = v0 + v1 + v2 + v3;
    for (int off = 32; off; off >>= 1) sum += __shfl_down(sum, off, 64);
    if (lane == 0) reds[wid] = sum;
    __syncthreads();
    sum = reds[0] + reds[1] + reds[2] + reds[3];

    float inv = 1.f / sum;
    ushort4 o;
    o.x = f2bf(v0 * inv); o.y = f2bf(v1 * inv);
    o.z = f2bf(v2 * inv); o.w = f2bf(v3 * inv);
    reinterpret_cast<ushort4*>(p)[threadIdx.x] = o;
}

extern "C" void kernel_launch(void* const* d_in, const int* in_sizes, int n_in,
                              void* d_out, int out_size, void* d_ws, size_t ws_size,
                              hipStream_t stream)
{
    const float* x        = (const float*)d_in[0];
    // d_in[1] = temb : unused by the reference
    const float* gn_scale = (const float*)d_in[2];
    const float* gn_bias  = (const float*)d_in[3];
    const float* wq = (const float*)d_in[4];
    const float* bq = (const float*)d_in[5];
    const float* wk = (const float*)d_in[6];
    const float* bk = (const float*)d_in[7];
    const float* wv = (const float*)d_in[8];
    const float* bv = (const float*)d_in[9];
    const float* wo = (const float*)d_in[10];
    const float* bo = (const float*)d_in[11];
    float* out = (float*)d_out;

    // workspace layout (bf16 elements)
    short* ws = (short*)d_ws;
    const size_t E = (size_t)B_ * C_ * HW_;        // 8388608
    short* hn_t = ws;                              // [b][i][c]
    short* q_t  = hn_t + E;                        // [b][i][c]
    short* k_t  = q_t + E;                         // [b][i][c]
    short* v    = k_t + E;                         // [b][c][j]
    short* ao_t = v + E;                           // [b][i][c]
    short* attn = ao_t + E;                        // [b][i][j]  (B*HW*HW)
    short* wsq  = attn + (size_t)B_ * HW2;
    short* wsk  = wsq + (size_t)C_ * C_;
    short* wsv  = wsk + (size_t)C_ * C_;
    short* wso  = wsv + (size_t)C_ * C_;
    float2* stats = (float2*)(wso + (size_t)C_ * C_);   // 512 float2

    const float inv_sqrt_c = 0.044194173824159216f;   // 512^-0.5

    f2bf4_kernel<<<dim3(1024), 256, 0, stream>>>(
        wq, wk, wv, wo,
        (unsigned short*)wsq, (unsigned short*)wsk,
        (unsigned short*)wsv, (unsigned short*)wso);

    gn_stats<<<dim3(B_ * G_), 256, 0, stream>>>(x, stats);
    gn_apply<<<dim3(HW_ / 64, C_ / 64, B_), 256, 0, stream>>>(
        x, stats, gn_scale, gn_bias, (unsigned short*)hn_t);

    // q_t[i][co] = sum_c hn_t[i][c] * wq[co][c] + bq[co]   (per-col bias)
    dim3 gq(C_ / 128, HW_ / 128, B_);              // (4, 8, 16)
    gemm_nt<0, 2, 0><<<gq, 256, 0, stream>>>(
        hn_t, CHW, wsq, 0, q_t, CHW, C_, bq, nullptr, 0, C_, 1.0f);
    gemm_nt<0, 2, 0><<<gq, 256, 0, stream>>>(
        hn_t, CHW, wsk, 0, k_t, CHW, C_, bk, nullptr, 0, C_, 1.0f);

    // v[co][j] = sum_c wv[co][c] * hn_t[j][c] + bv[co]     (per-row bias)
    dim3 gv(HW_ / 128, C_ / 128, B_);              // (8, 4, 16)
    gemm_nt<0, 1, 0><<<gv, 256, 0, stream>>>(
        wsv, 0, hn_t, CHW, v, CHW, HW_, bv, nullptr, 0, C_, 1.0f);

    // attn[i][j] = (sum_c q_t[i][c] * k_t[j][c]) * C^-0.5
    dim3 gs(HW_ / 128, HW_ / 128, B_);             // (8, 8, 16)
    gemm_nt<0, 0, 0><<<gs, 256, 0, stream>>>(
        q_t, CHW, k_t, CHW, attn, HW2, HW_, nullptr, nullptr, 0, C_, inv_sqrt_c);

    softmax_kernel<<<dim3(B_ * HW_), 256, 0, stream>>>((unsigned short*)attn);

    // ao_t[i][c] = sum_j attn[i][j] * v[c][j]
    dim3 gp(C_ / 128, HW_ / 128, B_);              // (4, 8, 16)
    gemm_nt<0, 0, 0><<<gp, 256, 0, stream>>>(
        attn, HW2, v, CHW, ao_t, CHW, C_, nullptr, nullptr, 0, HW_, 1.0f);

    // out[co][i] = x + sum_c wo[co][c] * ao_t[i][c] + bo[co]
    dim3 go(HW_ / 128, C_ / 128, B_);              // (8, 4, 16)
    gemm_nt<1, 1, 1><<<go, 256, 0, stream>>>(
        wso, 0, ao_t, CHW, out, CHW, HW_, bo, x, CHW, C_, 1.0f);
}

// Round 4
// 172.056 us; speedup vs baseline: 5.6855x; 1.1060x over previous
//
#include <hip/hip_runtime.h>

#define B_   16
#define C_   512
#define HW_  1024
#define G_   32
#define CPG  16
#define EPS  1e-5f
#define CHW  ((size_t)C_ * HW_)        // 524288 elements per batch (c,hw)
#define HW2  ((size_t)HW_ * HW_)       // 1048576 elements per batch (hw,hw)

typedef __attribute__((ext_vector_type(8))) short bf16x8;
typedef __attribute__((ext_vector_type(4))) float f32x4;

__device__ inline unsigned short f2bf(float f) {
    union { float f; unsigned u; } v; v.f = f;
    unsigned r = v.u + 0x7fffu + ((v.u >> 16) & 1u);   // RNE
    return (unsigned short)(r >> 16);
}
__device__ inline float bf2f(unsigned short h) {
    union { unsigned u; float f; } v; v.u = (unsigned)h << 16;
    return v.f;
}

__device__ inline void gload_lds16(const void* g, void* lds) {
    __builtin_amdgcn_global_load_lds(
        (const __attribute__((address_space(1))) void*)g,
        (__attribute__((address_space(3))) void*)lds,
        16, 0, 0);
}

// ---------------- fp32 -> bf16 weight convert (all 4 weights, one launch) ----
__global__ __launch_bounds__(256) void f2bf4_kernel(
    const float* __restrict__ w0, const float* __restrict__ w1,
    const float* __restrict__ w2, const float* __restrict__ w3,
    unsigned short* __restrict__ o0, unsigned short* __restrict__ o1,
    unsigned short* __restrict__ o2, unsigned short* __restrict__ o3)
{
    int wsel = blockIdx.x >> 8;
    int blk  = blockIdx.x & 255;
    const float* in = (wsel == 0) ? w0 : (wsel == 1) ? w1 : (wsel == 2) ? w2 : w3;
    unsigned short* out = (wsel == 0) ? o0 : (wsel == 1) ? o1 : (wsel == 2) ? o2 : o3;
    int i = (blk * 256 + threadIdx.x) * 4;
    float4 f = *reinterpret_cast<const float4*>(in + i);
    ushort4 o;
    o.x = f2bf(f.x); o.y = f2bf(f.y); o.z = f2bf(f.z); o.w = f2bf(f.w);
    *reinterpret_cast<ushort4*>(out + i) = o;
}

// ---------------- concat bq||bk -> bqk[1024] ----------------
__global__ __launch_bounds__(256) void bias_concat(
    const float* __restrict__ bq, const float* __restrict__ bk,
    float* __restrict__ bqk)
{
    const float* src = blockIdx.x ? bk : bq;
    bqk[blockIdx.x * 512 + threadIdx.x]       = src[threadIdx.x];
    bqk[blockIdx.x * 512 + 256 + threadIdx.x] = src[256 + threadIdx.x];
}

// ---------------- GN pass 1: per-(b,g) mean / rsqrt(var) ----------------
__global__ __launch_bounds__(256) void gn_stats(const float* __restrict__ x,
                                                float2* __restrict__ stats)
{
    int bg = blockIdx.x;                                  // 0..511
    const float4* xp = reinterpret_cast<const float4*>(x + (size_t)bg * CPG * HW_);
    const int N = CPG * HW_;                              // 16384

    float s = 0.f, ss = 0.f;
#pragma unroll
    for (int k = 0; k < 16; ++k) {
        float4 v = xp[threadIdx.x + k * 256];
        s  += v.x + v.y + v.z + v.w;
        ss += v.x * v.x + v.y * v.y + v.z * v.z + v.w * v.w;
    }
    for (int off = 32; off; off >>= 1) {
        s  += __shfl_down(s,  off, 64);
        ss += __shfl_down(ss, off, 64);
    }
    __shared__ float red0[4], red1[4];
    int lane = threadIdx.x & 63, wid = threadIdx.x >> 6;
    if (lane == 0) { red0[wid] = s; red1[wid] = ss; }
    __syncthreads();
    if (threadIdx.x == 0) {
        float S  = red0[0] + red0[1] + red0[2] + red0[3];
        float SS = red1[0] + red1[1] + red1[2] + red1[3];
        float mu = S / (float)N;
        float var = SS / (float)N - mu * mu;
        stats[bg] = make_float2(mu, rsqrtf(var + EPS));
    }
}

// ---------------- GN pass 2: normalize + transpose -> bf16 hn_t[b][i][c] ----
__global__ __launch_bounds__(256) void gn_apply(
    const float* __restrict__ x, const float2* __restrict__ stats,
    const float* __restrict__ scale, const float* __restrict__ bias,
    unsigned short* __restrict__ hn_t)
{
    __shared__ unsigned short tile[64][72];

    const int b  = blockIdx.z;
    const int c0 = blockIdx.y * 64;
    const int i0 = blockIdx.x * 64;
    const int t  = threadIdx.x;

    const int r = t >> 2;
    const int q = t & 3;
    const int c = c0 + r;

    float2 st = stats[b * G_ + (c >> 4)];
    float scl = scale[c] * st.y;
    float bia = bias[c] - st.x * scl;

    const float* xp = x + ((size_t)b * C_ + c) * HW_ + i0 + q * 16;
#pragma unroll
    for (int u = 0; u < 4; ++u) {
        float4 v = *reinterpret_cast<const float4*>(xp + u * 4);
        int il = q * 16 + u * 4;
        tile[il + 0][r] = f2bf(v.x * scl + bia);
        tile[il + 1][r] = f2bf(v.y * scl + bia);
        tile[il + 2][r] = f2bf(v.z * scl + bia);
        tile[il + 3][r] = f2bf(v.w * scl + bia);
    }
    __syncthreads();

    const int il = t >> 2;
    unsigned short* dst = hn_t + ((size_t)b * HW_ + i0 + il) * C_ + c0;
    *reinterpret_cast<uint4*>(dst + q * 8)        = *reinterpret_cast<uint4*>(&tile[il][q * 8]);
    *reinterpret_cast<uint4*>(dst + (q + 4) * 8)  = *reinterpret_cast<uint4*>(&tile[il][(q + 4) * 8]);
}

// ---------------- NT bf16 MFMA GEMM, double-buffered + counted vmcnt -------
// C[m][n] = alpha * sum_k A[m*ldA+k] * B[n*ldB+k]  (+bias) (+res)
// 128x128 tile, BK=32, 256 thr = 4 waves (2x2), 4x4 16x16x32 frags per wave.
// BIASMODE: 0 none, 1 per-row bias[m], 2 per-col bias[n].
template<int OUTF32, int BIASMODE, int HASRES>
__global__ __launch_bounds__(256) void gemm_db(
    const short* __restrict__ A, size_t sA, int ldA,
    const short* __restrict__ Bm, size_t sB, int ldB,
    void* __restrict__ Cm, size_t sC, int ldC,
    const float* __restrict__ bias,
    const float* __restrict__ res, size_t sR,
    int K, float alpha)
{
    __shared__ __align__(16) short lA[2][128 * 32];   // 2 x 8 KB
    __shared__ __align__(16) short lB[2][128 * 32];   // 2 x 8 KB

    const int bz = blockIdx.z;
    const short* Ab = A  + (size_t)bz * sA;
    const short* Bb = Bm + (size_t)bz * sB;

    const int m0 = blockIdx.y * 128;
    const int n0 = blockIdx.x * 128;

    const int t = threadIdx.x;
    const int wv = t >> 6, lane = t & 63;
    const int wrow = (wv >> 1) * 64, wcol = (wv & 1) * 64;

    const int sm = lane >> 2;            // staging: row within 16-row chunk
    const int sk = (lane & 3) * 8;       // staging: k element offset
    const int fr = lane & 15;            // fragment row (A) / col (B)
    const int kb = (lane >> 4) * 8;      // fragment k element offset
    const int c0g = 2 * wv, c1g = 2 * wv + 1;   // this wave's staging chunks

    auto stage = [&](int buf, int tt) {
        const int k0 = tt * 32;
        gload_lds16(Ab + (size_t)(m0 + c0g * 16 + sm) * ldA + k0 + sk, &lA[buf][c0g * 512]);
        gload_lds16(Ab + (size_t)(m0 + c1g * 16 + sm) * ldA + k0 + sk, &lA[buf][c1g * 512]);
        gload_lds16(Bb + (size_t)(n0 + c0g * 16 + sm) * ldB + k0 + sk, &lB[buf][c0g * 512]);
        gload_lds16(Bb + (size_t)(n0 + c1g * 16 + sm) * ldB + k0 + sk, &lB[buf][c1g * 512]);
    };

    f32x4 zero = {0.f, 0.f, 0.f, 0.f};
    f32x4 acc[4][4];
#pragma unroll
    for (int i = 0; i < 4; ++i)
#pragma unroll
        for (int j = 0; j < 4; ++j) acc[i][j] = zero;

    const int T = K / 32;

    // prologue: 2-deep prefetch; wait only for tile 0 (vmcnt(4) leaves t1 in flight)
    stage(0, 0);
    stage(1, 1);
    asm volatile("s_waitcnt vmcnt(4)\n\ts_barrier" ::: "memory");
    __builtin_amdgcn_sched_barrier(0);

    int cur = 0;
    for (int tt = 0; tt < T; ++tt) {
        bf16x8 af[4], bfg[4];
#pragma unroll
        for (int f = 0; f < 4; ++f) {
            af[f]  = *reinterpret_cast<const bf16x8*>(&lA[cur][(wrow + f * 16 + fr) * 32 + kb]);
            bfg[f] = *reinterpret_cast<const bf16x8*>(&lB[cur][(wcol + f * 16 + fr) * 32 + kb]);
        }
        // all waves done reading buf[cur] -> safe to overwrite after barrier
        asm volatile("s_waitcnt lgkmcnt(0)\n\ts_barrier" ::: "memory");
        __builtin_amdgcn_sched_barrier(0);

        if (tt + 2 < T) stage(cur, tt + 2);

        __builtin_amdgcn_s_setprio(1);
#pragma unroll
        for (int i = 0; i < 4; ++i)
#pragma unroll
            for (int j = 0; j < 4; ++j)
                acc[i][j] = __builtin_amdgcn_mfma_f32_16x16x32_bf16(af[i], bfg[j], acc[i][j], 0, 0, 0);
        __builtin_amdgcn_s_setprio(0);
        __builtin_amdgcn_sched_barrier(0);

        // counted wait: leave the newest 4 loads (tile tt+2) in flight
        if (tt + 2 < T) {
            asm volatile("s_waitcnt vmcnt(4)\n\ts_barrier" ::: "memory");
        } else if (tt + 1 < T) {
            asm volatile("s_waitcnt vmcnt(0)\n\ts_barrier" ::: "memory");
        }
        __builtin_amdgcn_sched_barrier(0);
        cur ^= 1;
    }

    // C/D layout: col = lane&15, row = (lane>>4)*4 + reg  [m89-verified]
    const int rq = (lane >> 4) * 4;
#pragma unroll
    for (int i = 0; i < 4; ++i) {
#pragma unroll
        for (int rg = 0; rg < 4; ++rg) {
            int row = m0 + wrow + i * 16 + rq + rg;
            float bm = (BIASMODE == 1) ? bias[row] : 0.f;
#pragma unroll
            for (int j = 0; j < 4; ++j) {
                int col = n0 + wcol + j * 16 + fr;
                float vv = acc[i][j][rg] * alpha + bm;
                if (BIASMODE == 2) vv += bias[col];
                size_t off = (size_t)row * ldC + col;
                if (HASRES) vv += res[(size_t)bz * sR + off];
                if (OUTF32) ((float*)Cm)[(size_t)bz * sC + off] = vv;
                else ((unsigned short*)Cm)[(size_t)bz * sC + off] = f2bf(vv);
            }
        }
    }
}

// ---------------- in-place bf16 row softmax over 1024 ----------------
__global__ __launch_bounds__(256) void softmax_kernel(unsigned short* __restrict__ attn)
{
    size_t row = blockIdx.x;
    unsigned short* p = attn + row * HW_;
    ushort4 raw = reinterpret_cast<ushort4*>(p)[threadIdx.x];
    float v0 = bf2f(raw.x), v1 = bf2f(raw.y), v2 = bf2f(raw.z), v3 = bf2f(raw.w);

    float mx = fmaxf(fmaxf(v0, v1), fmaxf(v2, v3));
    for (int off = 32; off; off >>= 1) mx = fmaxf(mx, __shfl_down(mx, off, 64));
    __shared__ float redm[4], reds[4];
    int lane = threadIdx.x & 63, wid = threadIdx.x >> 6;
    if (lane == 0) redm[wid] = mx;
    __syncthreads();
    mx = fmaxf(fmaxf(redm[0], redm[1]), fmaxf(redm[2], redm[3]));

    v0 = __expf(v0 - mx); v1 = __expf(v1 - mx);
    v2 = __expf(v2 - mx); v3 = __expf(v3 - mx);
    float sum = v0 + v1 + v2 + v3;
    for (int off = 32; off; off >>= 1) sum += __shfl_down(sum, off, 64);
    if (lane == 0) reds[wid] = sum;
    __syncthreads();
    sum = reds[0] + reds[1] + reds[2] + reds[3];

    float inv = 1.f / sum;
    ushort4 o;
    o.x = f2bf(v0 * inv); o.y = f2bf(v1 * inv);
    o.z = f2bf(v2 * inv); o.w = f2bf(v3 * inv);
    reinterpret_cast<ushort4*>(p)[threadIdx.x] = o;
}

extern "C" void kernel_launch(void* const* d_in, const int* in_sizes, int n_in,
                              void* d_out, int out_size, void* d_ws, size_t ws_size,
                              hipStream_t stream)
{
    const float* x        = (const float*)d_in[0];
    // d_in[1] = temb : unused by the reference
    const float* gn_scale = (const float*)d_in[2];
    const float* gn_bias  = (const float*)d_in[3];
    const float* wq = (const float*)d_in[4];
    const float* bq = (const float*)d_in[5];
    const float* wk = (const float*)d_in[6];
    const float* bk = (const float*)d_in[7];
    const float* wv = (const float*)d_in[8];
    const float* bv = (const float*)d_in[9];
    const float* wo = (const float*)d_in[10];
    const float* bo = (const float*)d_in[11];
    float* out = (float*)d_out;

    // workspace layout (bf16 elements)
    short* ws = (short*)d_ws;
    const size_t E = (size_t)B_ * C_ * HW_;        // 8388608
    short* hn_t = ws;                              // [b][i][c]          E
    short* qk_t = hn_t + E;                        // [b*i][q||k]        2E
    short* v    = qk_t + 2 * E;                    // [b][c][j]          E
    short* ao_t = v + E;                           // [b][i][c]          E
    short* attn = ao_t + E;                        // [b][i][j]          2E
    short* wsq  = attn + 2 * E;                    // wq||wk||wv||wo bf16
    short* wsk  = wsq + (size_t)C_ * C_;
    short* wsv  = wsk + (size_t)C_ * C_;
    short* wso  = wsv + (size_t)C_ * C_;
    float* bqk  = (float*)(wso + (size_t)C_ * C_); // 1024 f32
    float2* stats = (float2*)(bqk + 1024);         // 512 float2

    const float inv_sqrt_c = 0.044194173824159216f;   // 512^-0.5

    f2bf4_kernel<<<dim3(1024), 256, 0, stream>>>(
        wq, wk, wv, wo,
        (unsigned short*)wsq, (unsigned short*)wsk,
        (unsigned short*)wsv, (unsigned short*)wso);
    bias_concat<<<dim3(2), 256, 0, stream>>>(bq, bk, bqk);

    gn_stats<<<dim3(B_ * G_), 256, 0, stream>>>(x, stats);
    gn_apply<<<dim3(HW_ / 64, C_ / 64, B_), 256, 0, stream>>>(
        x, stats, gn_scale, gn_bias, (unsigned short*)hn_t);

    // fused QK projection: qk_t[m][n] = sum_c hn_t[m][c] * (wq||wk)[n][c] + bqk[n]
    // m = b*1024+i (16384 rows), n = 0..1023
    dim3 gqk(HW_ / 128, (B_ * HW_) / 128, 1);      // (8, 128, 1)
    gemm_db<0, 2, 0><<<gqk, 256, 0, stream>>>(
        hn_t, 0, C_, wsq, 0, C_, qk_t, 0, HW_, bqk, nullptr, 0, C_, 1.0f);

    // v[c][j] = sum_k wv[c][k] * hn_t[j][k] + bv[c]
    dim3 gv(HW_ / 128, C_ / 128, B_);              // (8, 4, 16)
    gemm_db<0, 1, 0><<<gv, 256, 0, stream>>>(
        wsv, 0, C_, hn_t, CHW, C_, v, CHW, HW_, bv, nullptr, 0, C_, 1.0f);

    // attn[i][j] = (sum_c q[i][c] * k[j][c]) * C^-0.5   (q,k inside qk_t)
    dim3 gs(HW_ / 128, HW_ / 128, B_);             // (8, 8, 16)
    gemm_db<0, 0, 0><<<gs, 256, 0, stream>>>(
        qk_t, HW2, HW_, qk_t + C_, HW2, HW_, attn, HW2, HW_,
        nullptr, nullptr, 0, C_, inv_sqrt_c);

    softmax_kernel<<<dim3(B_ * HW_), 256, 0, stream>>>((unsigned short*)attn);

    // ao_t[i][c] = sum_j attn[i][j] * v[c][j]
    dim3 gp(C_ / 128, HW_ / 128, B_);              // (4, 8, 16)
    gemm_db<0, 0, 0><<<gp, 256, 0, stream>>>(
        attn, HW2, HW_, v, CHW, HW_, ao_t, CHW, C_, nullptr, nullptr, 0, HW_, 1.0f);

    // out[c][i] = x + sum_k wo[c][k] * ao_t[i][k] + bo[c]
    dim3 go(HW_ / 128, C_ / 128, B_);              // (8, 4, 16)
    gemm_db<1, 1, 1><<<go, 256, 0, stream>>>(
        wso, 0, C_, ao_t, CHW, C_, out, CHW, HW_, bo, x, CHW, C_, 1.0f);
}